// Round 7
// baseline (10257.496 us; speedup 1.0000x reference)
//
#include <hip/hip_runtime.h>
#include <math.h>

#define TENC 256
#define NIE  6
#define LH   68    // h row stride (floats): 16B-aligned rows; 2-way bank alias = free
#define WSTR 68    // U1 LDS row stride: jg offsets land on banks {0,24,16,8}

// ---- LDS: 52,224 (sU1) + 528 (sHd) + 4*17,408 (h dbuf) = 122,384 B ----
__shared__ float sU1[192 * WSTR];   // [(j*3+g)*WSTR + k]
__shared__ float sHd[132];          // [0:64) Wcv, [64:128) Won
__shared__ float sh0a[64 * LH], sh0b[64 * LH];
__shared__ float sh1a[64 * LH], sh1b[64 * LH];

__device__ __forceinline__ float sigm_(float x) { return 1.0f / (1.0f + expf(-x)); }

__device__ __forceinline__ void fma4(float& acc, const float4& a, const float4& b) {
    acc = fmaf(a.x, b.x, acc);
    acc = fmaf(a.y, b.y, acc);
    acc = fmaf(a.z, b.z, acc);
    acc = fmaf(a.w, b.w, acc);
}

__device__ __forceinline__ void stage_u1(const float* __restrict__ U1) {
    for (int s = threadIdx.x; s < 12288; s += 512) {
        int k = s & 63, row = s >> 6;          // row = g*64 + j (global layout)
        int g = row >> 6, j = row & 63;
        sU1[(j * 3 + g) * WSTR + k] = U1[s];   // j-major in LDS
    }
}

// layer 0: W0 in regs, U0 from global (L2-hot), h from LDS read-buffer h0r.
template<int KIN>
__device__ __forceinline__ void layer0_c(const float* __restrict__ U0,
                                         const float* w0r, const float* w0z,
                                         const float* w0n,          // [2*KIN] regs
                                         const float* xin,          // [4*KIN] regs
                                         const float* b_r, const float* b_z,
                                         const float* b_nx, const float* b_nh,
                                         const float* __restrict__ h0r,
                                         int jB, int bl, float hn[2][4])
{
    float ar[2][4], az[2][4], anx[2][4], anh[2][4];
#pragma unroll
    for (int g = 0; g < 4; ++g)
#pragma unroll
        for (int jj = 0; jj < 2; ++jj) {
            ar[jj][g] = b_r[jj]; az[jj][g] = b_z[jj];
            anx[jj][g] = b_nx[jj]; anh[jj][g] = b_nh[jj];
        }
#pragma unroll
    for (int jj = 0; jj < 2; ++jj)
#pragma unroll
        for (int g = 0; g < 4; ++g)
#pragma unroll
            for (int k = 0; k < KIN; ++k) {
                ar[jj][g]  = fmaf(w0r[jj * KIN + k], xin[g * KIN + k], ar[jj][g]);
                az[jj][g]  = fmaf(w0z[jj * KIN + k], xin[g * KIN + k], az[jj][g]);
                anx[jj][g] = fmaf(w0n[jj * KIN + k], xin[g * KIN + k], anx[jj][g]);
            }
    const float* u0 = U0 + (size_t)jB * 64;
    const float* u1 = U0 + (size_t)(jB + 1) * 64;
    const float* hr0 = h0r + bl * LH;
#pragma unroll 2
    for (int kc = 0; kc < 64; kc += 4) {
        float4 hv[4];
#pragma unroll
        for (int g = 0; g < 4; ++g)
            hv[g] = *(const float4*)(hr0 + g * (16 * LH) + kc);
        float4 r0 = *(const float4*)(u0 + kc);
        float4 z0 = *(const float4*)(u0 + 4096 + kc);
        float4 n0 = *(const float4*)(u0 + 8192 + kc);
        float4 r1 = *(const float4*)(u1 + kc);
        float4 z1 = *(const float4*)(u1 + 4096 + kc);
        float4 n1 = *(const float4*)(u1 + 8192 + kc);
#pragma unroll
        for (int g = 0; g < 4; ++g) {
            fma4(ar[0][g], r0, hv[g]); fma4(az[0][g], z0, hv[g]); fma4(anh[0][g], n0, hv[g]);
            fma4(ar[1][g], r1, hv[g]); fma4(az[1][g], z1, hv[g]); fma4(anh[1][g], n1, hv[g]);
        }
    }
#pragma unroll
    for (int g = 0; g < 4; ++g) {
        float2 ho = *(const float2*)(h0r + (bl + 16 * g) * LH + jB);
        float hold[2] = {ho.x, ho.y};
#pragma unroll
        for (int jj = 0; jj < 2; ++jj) {
            float r = sigm_(ar[jj][g]);
            float z = sigm_(az[jj][g]);
            float n = tanhf(fmaf(r, anh[jj][g], anx[jj][g]));
            hn[jj][g] = fmaf(z, hold[jj] - n, n);
        }
    }
}

// layer 1: x = x0r (h0_new buffer), h = h1r; W1 from GLOBAL (L2), U1 from LDS.
__device__ __forceinline__ void layer1_c(const float* __restrict__ W1,
                                         const float* b_r, const float* b_z,
                                         const float* b_nx, const float* b_nh,
                                         const float* __restrict__ x0r,
                                         const float* __restrict__ h1r,
                                         int jB, int bl, float hn[2][4])
{
    float ar[2][4], az[2][4], anx[2][4], anh[2][4];
#pragma unroll
    for (int g = 0; g < 4; ++g)
#pragma unroll
        for (int jj = 0; jj < 2; ++jj) {
            ar[jj][g] = b_r[jj]; az[jj][g] = b_z[jj];
            anx[jj][g] = b_nx[jj]; anh[jj][g] = b_nh[jj];
        }
    const float* wp = W1 + (size_t)jB * 64;         // rows: +0(r) +4096(z) +8192(n); j+1 at +64
    const float* ub0 = sU1 + (jB * 3) * WSTR;
    const float* ub1 = sU1 + ((jB + 1) * 3) * WSTR;
    const float* xr0 = x0r + bl * LH;
    const float* hr0 = h1r + bl * LH;
#pragma unroll 2
    for (int kc = 0; kc < 64; kc += 4) {
        float4 wr0 = *(const float4*)(wp + kc);
        float4 wz0 = *(const float4*)(wp + 4096 + kc);
        float4 wn0 = *(const float4*)(wp + 8192 + kc);
        float4 wr1 = *(const float4*)(wp + 64 + kc);
        float4 wz1 = *(const float4*)(wp + 4160 + kc);
        float4 wn1 = *(const float4*)(wp + 8256 + kc);
        float4 xv[4], hv[4];
#pragma unroll
        for (int g = 0; g < 4; ++g) {
            xv[g] = *(const float4*)(xr0 + g * (16 * LH) + kc);
            hv[g] = *(const float4*)(hr0 + g * (16 * LH) + kc);
        }
        float4 ur0 = *(const float4*)(ub0 + kc);
        float4 uz0 = *(const float4*)(ub0 + WSTR + kc);
        float4 un0 = *(const float4*)(ub0 + 2 * WSTR + kc);
        float4 ur1 = *(const float4*)(ub1 + kc);
        float4 uz1 = *(const float4*)(ub1 + WSTR + kc);
        float4 un1 = *(const float4*)(ub1 + 2 * WSTR + kc);
#pragma unroll
        for (int g = 0; g < 4; ++g) {
            fma4(ar[0][g], wr0, xv[g]);  fma4(ar[0][g], ur0, hv[g]);
            fma4(az[0][g], wz0, xv[g]);  fma4(az[0][g], uz0, hv[g]);
            fma4(anx[0][g], wn0, xv[g]); fma4(anh[0][g], un0, hv[g]);
            fma4(ar[1][g], wr1, xv[g]);  fma4(ar[1][g], ur1, hv[g]);
            fma4(az[1][g], wz1, xv[g]);  fma4(az[1][g], uz1, hv[g]);
            fma4(anx[1][g], wn1, xv[g]); fma4(anh[1][g], un1, hv[g]);
        }
    }
#pragma unroll
    for (int g = 0; g < 4; ++g) {
        float2 ho = *(const float2*)(h1r + (bl + 16 * g) * LH + jB);
        float hold[2] = {ho.x, ho.y};
#pragma unroll
        for (int jj = 0; jj < 2; ++jj) {
            float r = sigm_(ar[jj][g]);
            float z = sigm_(az[jj][g]);
            float n = tanhf(fmaf(r, anh[jj][g], anx[jj][g]));
            hn[jj][g] = fmaf(z, hold[jj] - n, n);
        }
    }
}

extern "C" __global__ void __launch_bounds__(512, 2)
ccseq_kernel(const float* __restrict__ x, const int* __restrict__ p_tlen,
             const float* __restrict__ eW0, const float* __restrict__ eU0,
             const float* __restrict__ eBi0, const float* __restrict__ eBh0,
             const float* __restrict__ eW1, const float* __restrict__ eU1,
             const float* __restrict__ eBi1, const float* __restrict__ eBh1,
             const float* __restrict__ dW0, const float* __restrict__ dU0,
             const float* __restrict__ dBi0, const float* __restrict__ dBh0,
             const float* __restrict__ dW1, const float* __restrict__ dU1,
             const float* __restrict__ dBi1, const float* __restrict__ dBh1,
             const float* __restrict__ Won, const float* __restrict__ bon,
             const float* __restrict__ Wcv, const float* __restrict__ bcv,
             float* __restrict__ out)
{
    const int tid  = threadIdx.x;
    const int lane = tid & 63;
    const int wv   = tid >> 6;          // 0..7
    const int jg   = lane >> 4;         // 0..3
    const int bl   = lane & 15;         // 0..15
    const int jB   = wv * 8 + jg * 2;   // this lane's 2 hidden units
    const int tlen = p_tlen[0];

    if (tid < 64) { sHd[tid] = Wcv[tid]; sHd[64 + tid] = Won[tid]; }
    for (int i = tid; i < 64 * LH; i += 512) {
        sh0a[i] = 0.0f; sh0b[i] = 0.0f; sh1a[i] = 0.0f; sh1b[i] = 0.0f;
    }
    stage_u1(eU1);
    __syncthreads();

    float* r0 = sh0a; float* w0 = sh0b;   // h0 read/write buffers
    float* r1 = sh1a; float* w1 = sh1b;   // h1 read/write buffers

    // ---- hoisted per-lane constants (encoder) ----
    float w0r[2 * NIE], w0z[2 * NIE], w0n[2 * NIE];
#pragma unroll
    for (int jj = 0; jj < 2; ++jj)
#pragma unroll
        for (int k = 0; k < NIE; ++k) {
            w0r[jj * NIE + k] = eW0[(jB + jj) * NIE + k];
            w0z[jj * NIE + k] = eW0[(64 + jB + jj) * NIE + k];
            w0n[jj * NIE + k] = eW0[(128 + jB + jj) * NIE + k];
        }
    float eb_r[2], eb_z[2], eb_nx[2], eb_nh[2];
    float e1_r[2], e1_z[2], e1_nx[2], e1_nh[2];
#pragma unroll
    for (int jj = 0; jj < 2; ++jj) {
        int j = jB + jj;
        eb_r[jj]  = eBi0[j] + eBh0[j];
        eb_z[jj]  = eBi0[64 + j] + eBh0[64 + j];
        eb_nx[jj] = eBi0[128 + j];
        eb_nh[jj] = eBh0[128 + j];
        e1_r[jj]  = eBi1[j] + eBh1[j];
        e1_z[jj]  = eBi1[64 + j] + eBh1[64 + j];
        e1_nx[jj] = eBi1[128 + j];
        e1_nh[jj] = eBh1[128 + j];
    }

    const size_t bstr = (size_t)TENC * NIE;
    const float* xb[4];
#pragma unroll
    for (int g = 0; g < 4; ++g)
        xb[g] = x + (size_t)(blockIdx.x * 64 + bl + 16 * g) * bstr;

    // ---------------- encoder ----------------
    float xc[4 * NIE], xn[4 * NIE];
#pragma unroll
    for (int g = 0; g < 4; ++g) {
        float2 p0 = *(const float2*)(xb[g]);
        float2 p1 = *(const float2*)(xb[g] + 2);
        float2 p2 = *(const float2*)(xb[g] + 4);
        xc[g * NIE + 0] = p0.x; xc[g * NIE + 1] = p0.y;
        xc[g * NIE + 2] = p1.x; xc[g * NIE + 3] = p1.y;
        xc[g * NIE + 4] = p2.x; xc[g * NIE + 5] = p2.y;
    }

    for (int t = 0; t < TENC; ++t) {
        const int tn = (t + 1 < TENC) ? (t + 1) : t;
#pragma unroll
        for (int g = 0; g < 4; ++g) {                  // 8B-aligned (tn*24 B)
            float2 p0 = *(const float2*)(xb[g] + tn * NIE);
            float2 p1 = *(const float2*)(xb[g] + tn * NIE + 2);
            float2 p2 = *(const float2*)(xb[g] + tn * NIE + 4);
            xn[g * NIE + 0] = p0.x; xn[g * NIE + 1] = p0.y;
            xn[g * NIE + 2] = p1.x; xn[g * NIE + 3] = p1.y;
            xn[g * NIE + 4] = p2.x; xn[g * NIE + 5] = p2.y;
        }

        float hn[2][4];
        layer0_c<NIE>(eU0, w0r, w0z, w0n, xc, eb_r, eb_z, eb_nx, eb_nh, r0, jB, bl, hn);
#pragma unroll
        for (int g = 0; g < 4; ++g)
            *(float2*)(w0 + (bl + 16 * g) * LH + jB) = make_float2(hn[0][g], hn[1][g]);
        __syncthreads();                       // w0 (h0_new) published; r0 reads drained

        layer1_c(eW1, e1_r, e1_z, e1_nx, e1_nh, w0, r1, jB, bl, hn);
#pragma unroll
        for (int g = 0; g < 4; ++g)
            *(float2*)(w1 + (bl + 16 * g) * LH + jB) = make_float2(hn[0][g], hn[1][g]);
        __syncthreads();                       // w1 (h1_new) published; r1 reads drained

        { float* tp = r0; r0 = w0; w0 = tp; }
        { float* tp = r1; r1 = w1; w1 = tp; }
#pragma unroll
        for (int i = 0; i < 4 * NIE; ++i) xc[i] = xn[i];
    }

    // ---------------- swap to decoder weights ----------------
    stage_u1(dU1);                             // safe: final barrier drained all sU1 reads
    float v0r[2], v0z[2], v0n[2];
    float db_r[2], db_z[2], db_nx[2], db_nh[2];
    float d1_r[2], d1_z[2], d1_nx[2], d1_nh[2];
#pragma unroll
    for (int jj = 0; jj < 2; ++jj) {
        int j = jB + jj;
        v0r[jj] = dW0[j]; v0z[jj] = dW0[64 + j]; v0n[jj] = dW0[128 + j];
        db_r[jj]  = dBi0[j] + dBh0[j];
        db_z[jj]  = dBi0[64 + j] + dBh0[64 + j];
        db_nx[jj] = dBi0[128 + j];
        db_nh[jj] = dBh0[128 + j];
        d1_r[jj]  = dBi1[j] + dBh1[j];
        d1_z[jj]  = dBi1[64 + j] + dBh1[64 + j];
        d1_nx[jj] = dBi1[128 + j];
        d1_nh[jj] = dBh1[128 + j];
    }
    const float hbc = bcv[0], hbo = bon[0];
    __syncthreads();

    // ---------------- decoder ----------------
    float prev[4] = {0.0f, 0.0f, 0.0f, 0.0f};
    for (int t = 0; t < tlen; ++t) {
        float hn[2][4];
        layer0_c<1>(dU0, v0r, v0z, v0n, prev, db_r, db_z, db_nx, db_nh, r0, jB, bl, hn);
#pragma unroll
        for (int g = 0; g < 4; ++g)
            *(float2*)(w0 + (bl + 16 * g) * LH + jB) = make_float2(hn[0][g], hn[1][g]);
        __syncthreads();

        layer1_c(dW1, d1_r, d1_z, d1_nx, d1_nh, w0, r1, jB, bl, hn);
#pragma unroll
        for (int g = 0; g < 4; ++g)
            *(float2*)(w1 + (bl + 16 * g) * LH + jB) = make_float2(hn[0][g], hn[1][g]);
        __syncthreads();                       // full h1_new (w1) readable

        // heads: every lane computes its own 4 batches
        float cv[4] = {hbc, hbc, hbc, hbc};
        float lg[4] = {hbo, hbo, hbo, hbo};
        const float* hr0 = w1 + bl * LH;
#pragma unroll 2
        for (int kc = 0; kc < 64; kc += 4) {
            float4 wc = *(const float4*)(sHd + kc);
            float4 wo = *(const float4*)(sHd + 64 + kc);
#pragma unroll
            for (int g = 0; g < 4; ++g) {
                float4 h4 = *(const float4*)(hr0 + g * (16 * LH) + kc);
                fma4(cv[g], wc, h4);
                fma4(lg[g], wo, h4);
            }
        }
#pragma unroll
        for (int g = 0; g < 4; ++g)
            prev[g] = (lg[g] > 0.0f) ? cv[g] : 0.0f;   // sigmoid(lg)>0.5 <=> lg>0
        if (tid < 16) {
#pragma unroll
            for (int g = 0; g < 4; ++g)
                out[(size_t)(blockIdx.x * 64 + bl + 16 * g) * tlen + t] = prev[g];
        }

        { float* tp = r0; r0 = w0; w0 = tp; }
        { float* tp = r1; r1 = w1; w1 = tp; }
    }
}

extern "C" void kernel_launch(void* const* d_in, const int* in_sizes, int n_in,
                              void* d_out, int out_size, void* d_ws, size_t ws_size,
                              hipStream_t stream)
{
    (void)n_in; (void)out_size; (void)d_ws; (void)ws_size;
    const float* x    = (const float*)d_in[0];
    const int*   tl   = (const int*)d_in[1];
    const float* eW0  = (const float*)d_in[2];
    const float* eU0  = (const float*)d_in[3];
    const float* eBi0 = (const float*)d_in[4];
    const float* eBh0 = (const float*)d_in[5];
    const float* eW1  = (const float*)d_in[6];
    const float* eU1  = (const float*)d_in[7];
    const float* eBi1 = (const float*)d_in[8];
    const float* eBh1 = (const float*)d_in[9];
    const float* dW0  = (const float*)d_in[10];
    const float* dU0  = (const float*)d_in[11];
    const float* dBi0 = (const float*)d_in[12];
    const float* dBh0 = (const float*)d_in[13];
    const float* dW1  = (const float*)d_in[14];
    const float* dU1  = (const float*)d_in[15];
    const float* dBi1 = (const float*)d_in[16];
    const float* dBh1 = (const float*)d_in[17];
    const float* Won  = (const float*)d_in[18];
    const float* bon  = (const float*)d_in[19];
    const float* Wcv  = (const float*)d_in[20];
    const float* bcv  = (const float*)d_in[21];

    const int B    = in_sizes[0] / (TENC * NIE);  // 16384
    const int nblk = B / 64;                      // 256 blocks, 1/CU

    ccseq_kernel<<<dim3(nblk), dim3(512), 0, stream>>>(
        x, tl, eW0, eU0, eBi0, eBh0, eW1, eU1, eBi1, eBh1,
        dW0, dU0, dBi0, dBh0, dW1, dU1, dBi1, dBh1,
        Won, bon, Wcv, bcv, (float*)d_out);
}